// Round 10
// baseline (444.104 us; speedup 1.0000x reference)
//
#include <hip/hip_runtime.h>
#include <hip/hip_bf16.h>

#define DM 256
#define NB 128
#define SQ 384
#define SK 384

typedef __bf16 bf16x4 __attribute__((ext_vector_type(4)));
typedef __bf16 bf16x8 __attribute__((ext_vector_type(8)));
typedef float f32x4 __attribute__((ext_vector_type(4)));
typedef unsigned short u16;
typedef unsigned int u32;

union BF8 { bf16x8 v8; bf16x4 v4[2]; uint2 u2[2]; };

__device__ __forceinline__ u16 f2bf(float f) {
    union { float fv; u32 u; } v; v.fv = f;
    u32 r = v.u + 0x7FFFu + ((v.u >> 16) & 1u);
    return (u16)(r >> 16);
}
__device__ __forceinline__ float bf2f(u16 u) {
    union { u32 v; float f; } x; x.v = ((u32)u) << 16; return x.f;
}
__device__ __forceinline__ uint2 pack4(float a, float b, float c, float d) {
    uint2 r;
    r.x = (u32)f2bf(a) | ((u32)f2bf(b) << 16);
    r.y = (u32)f2bf(c) | ((u32)f2bf(d) << 16);
    return r;
}
// native round-to-nearest-even f32->bf16 via compiler (v_cvt_pk_bf16_f32)
__device__ __forceinline__ uint2 pack4c(f32x4 v) {
    bf16x4 t;
    t[0] = (__bf16)v[0]; t[1] = (__bf16)v[1];
    t[2] = (__bf16)v[2]; t[3] = (__bf16)v[3];
    union { bf16x4 b; uint2 u; } cv; cv.b = t; return cv.u;
}

// ---------------------------------------------------------------------------
// prep_w: W[k][n] fp32 -> Wt[n][k] bf16. 5 matrices. q_w gets scale*log2(e)
// folded (softmax runs in exp2 domain).
// ---------------------------------------------------------------------------
__global__ __launch_bounds__(256)
void prep_w(const float* __restrict__ q_w, const float* __restrict__ k_w,
            const float* __restrict__ v_w, const float* __restrict__ g_w,
            const float* __restrict__ o_w, u16* __restrict__ wt)
{
    __shared__ float t[64][65];
    const int mat = blockIdx.z;
    const float* src = mat == 0 ? q_w : mat == 1 ? k_w : mat == 2 ? v_w : mat == 3 ? g_w : o_w;
    const float scale = (mat == 0) ? (float)(0.17677669529663687 * 1.4426950408889634) : 1.0f;
    const int k0 = blockIdx.x * 64, n0 = blockIdx.y * 64;
    const int tid = threadIdx.x;
#pragma unroll
    for (int i = 0; i < 4; ++i) {
        int pos = tid + i * 256;
        int r = pos >> 4, c4 = (pos & 15) * 4;
        f32x4 v = *(const f32x4*)&src[(size_t)(k0 + r) * DM + n0 + c4];
        t[r][c4 + 0] = v[0]; t[r][c4 + 1] = v[1]; t[r][c4 + 2] = v[2]; t[r][c4 + 3] = v[3];
    }
    __syncthreads();
    const int nr = tid >> 2, kq = (tid & 3) * 16;
    u16* dst = wt + (size_t)mat * DM * DM + (size_t)(n0 + nr) * DM + k0 + kq;
#pragma unroll
    for (int j = 0; j < 16; j += 4) {
        uint2 p = pack4(t[kq + j][nr] * scale, t[kq + j + 1][nr] * scale,
                        t[kq + j + 2][nr] * scale, t[kq + j + 3][nr] * scale);
        *(uint2*)&dst[j] = p;
    }
}

// ---------------------------------------------------------------------------
// proj_kernel: out = A[M,256] @ W[256,256] (+epilogue). A-frags in registers
// (A read once from HBM), Wt slabs staged in swizzled LDS.
// MODE 0: A=q_data fp32; sl<4: qb=bf16(q*scale fold), sl>=4: gate=bf16 sigmoid
// MODE 1: A=m_data fp32; sl<4: kb natural, sl>=4: v -> vT[b][c][kk] transposed
// MODE 2: A=wavg bf16;   4 slabs: out fp32 + o_bias
// ---------------------------------------------------------------------------
template<int MODE>
__global__ __launch_bounds__(256)
void proj_kernel(const float* __restrict__ Af, const u16* __restrict__ Abf,
                 const u16* __restrict__ Wt1, const u16* __restrict__ Wt2,
                 const float* __restrict__ gb, const float* __restrict__ ob,
                 u16* __restrict__ out1, u16* __restrict__ gate,
                 u16* __restrict__ vT, float* __restrict__ outf)
{
    __shared__ u16 Wlds[64 * 256];   // [n 64][k 256 permuted] XOR-swizzled
    const int tid = threadIdx.x, lane = tid & 63, w = tid >> 6;
    const int lr = lane & 15, lg = lane >> 4;
    const int m0 = blockIdx.x * 64;

    // A fragments: af[ks] covers k = ks*32 + {4lg+j, 16+4lg+j}, row m0+w*16+lr
    BF8 af[8];
    if (MODE <= 1) {
        const float* arow = Af + (size_t)(m0 + w * 16 + lr) * DM + 4 * lg;
#pragma unroll
        for (int ks = 0; ks < 8; ++ks) {
            f32x4 v0 = *(const f32x4*)&arow[ks * 32];
            f32x4 v1 = *(const f32x4*)&arow[ks * 32 + 16];
            af[ks].u2[0] = pack4(v0[0], v0[1], v0[2], v0[3]);
            af[ks].u2[1] = pack4(v1[0], v1[1], v1[2], v1[3]);
        }
    } else {
        const u16* arow = Abf + (size_t)(m0 + w * 16 + lr) * DM + 4 * lg;
#pragma unroll
        for (int ks = 0; ks < 8; ++ks) {
            af[ks].u2[0] = *(const uint2*)&arow[ks * 32];
            af[ks].u2[1] = *(const uint2*)&arow[ks * 32 + 16];
        }
    }

    const int NSLAB = (MODE == 2) ? 4 : 8;
    for (int sl = 0; sl < NSLAB; ++sl) {
        const u16* Wsrc = (sl < 4) ? Wt1 : Wt2;
        const int n0 = (sl & 3) * 64;
        if (sl) __syncthreads();
        // stage Wt slab: 64 n-rows x 256 k, permuted-contiguous + XOR swizzle
        // 64 rows x 32 chunks of 8 u16 = 2048 chunks; 256 thr x 8 iters.
#pragma unroll
        for (int i = 0; i < 8; ++i) {
            int pos = tid + i * 256;
            int nr = pos >> 5, c8 = (pos & 31) * 8;
            uint4 gv = *(const uint4*)&Wsrc[(size_t)(n0 + nr) * DM + c8];
            int within = c8 & 31;
            int pa2 = (c8 >> 5) * 64 + ((within >> 3) & 1) * 32 + (within >> 4) * 8;
            int sw = (nr & 7) << 4;
            char* rb_ = (char*)Wlds + nr * 512;
            *(uint2*)(rb_ + (pa2 ^ sw)) = make_uint2(gv.x, gv.y);
            *(uint2*)(rb_ + ((pa2 + 16) ^ sw)) = make_uint2(gv.z, gv.w);
        }
        __syncthreads();

        f32x4 acc[4];
#pragma unroll
        for (int nf = 0; nf < 4; ++nf) acc[nf] = (f32x4){0.f, 0.f, 0.f, 0.f};
#pragma unroll
        for (int ks = 0; ks < 8; ++ks) {
#pragma unroll
            for (int nf = 0; nf < 4; ++nf) {
                int row = nf * 16 + lr;
                bf16x8 bfr = *(const bf16x8*)((char*)Wlds + row * 512 +
                                              ((ks * 64 + lg * 16) ^ ((row & 7) << 4)));
                acc[nf] = __builtin_amdgcn_mfma_f32_16x16x32_bf16(af[ks].v8, bfr, acc[nf], 0, 0, 0);
            }
        }

        // epilogue: D row = m0+w*16+4lg+r, col = n0+nf*16+lr
#pragma unroll
        for (int nf = 0; nf < 4; ++nf) {
            int n = n0 + nf * 16 + lr;
            int gn = (sl & 3) * 64 + nf * 16 + lr;
            if (MODE == 0) {
                if (sl < 4) {
#pragma unroll
                    for (int r = 0; r < 4; ++r)
                        out1[(size_t)(m0 + w * 16 + 4 * lg + r) * DM + n] = f2bf(acc[nf][r]);
                } else {
                    float gbv = gb[gn];
#pragma unroll
                    for (int r = 0; r < 4; ++r)
                        gate[(size_t)(m0 + w * 16 + 4 * lg + r) * DM + gn] =
                            f2bf(1.f / (1.f + __expf(-(acc[nf][r] + gbv))));
                }
            } else if (MODE == 1) {
                if (sl < 4) {
#pragma unroll
                    for (int r = 0; r < 4; ++r)
                        out1[(size_t)(m0 + w * 16 + 4 * lg + r) * DM + n] = f2bf(acc[nf][r]);
                } else {
                    int bb = m0 / SQ;
                    int kkl = m0 - bb * SQ + w * 16 + 4 * lg;
                    *(uint2*)&vT[(size_t)(bb * DM + gn) * SK + kkl] =
                        pack4(acc[nf][0], acc[nf][1], acc[nf][2], acc[nf][3]);
                }
            } else {
                float obv = ob[n];
#pragma unroll
                for (int r = 0; r < 4; ++r)
                    outf[(size_t)(m0 + w * 16 + 4 * lg + r) * DM + n] = acc[nf][r] + obv;
            }
        }
    }
}

// ---------------------------------------------------------------------------
// attn R10: barrier-free, fixed-max exp2 softmax, FULL one-tile-ahead
// prefetch: K, V, AND combined bias C4 = (bias+nbias)*log2e - MFIX.
// Tile body: QK (consumes kf,c4 -> both die) | issue next-tile loads into
// the freed registers | exp2+pack+lsum | PV (consumes vf) | swap.
// kb loop rolled; launch_bounds(256,1) -> ~256 VGPR budget (R9-verified
// heuristic: hipcc targets 2x declared min waves/EU).
// ---------------------------------------------------------------------------
__device__ __forceinline__ void load_k4(const u16* kp, int k0, BF8 kf[4]) {
#pragma unroll
    for (int rb = 0; rb < 4; ++rb) {
        const u16* kr = kp + (size_t)(k0 + rb * 16) * DM;
        kf[rb].u2[0] = *(const uint2*)&kr[0];
        kf[rb].u2[1] = *(const uint2*)&kr[16];
    }
}
__device__ __forceinline__ void load_v4(const u16* vp, int k0, BF8 vf[2][2]) {
#pragma unroll
    for (int kc = 0; kc < 2; ++kc)
#pragma unroll
        for (int cf = 0; cf < 2; ++cf) {
            const u16* vr = vp + (size_t)(cf * 16) * SK + k0 + kc * 32;
            vf[kc][cf].u2[0] = *(const uint2*)&vr[0];
            vf[kc][cf].u2[1] = *(const uint2*)&vr[16];
        }
}
__device__ __forceinline__ void load_c4(const float* bp, const float* np, int k0,
                                        int lr, f32x4 c4[4][4]) {
    const float LOG2E = 1.4426950408889634f;
    const float MFIX = 20.0f;
#pragma unroll
    for (int nf = 0; nf < 4; ++nf) {
        const float* bpr = bp + (size_t)(nf * 16 + lr) * SK + k0;
        const float* npr = np + (size_t)(nf * 16 + lr) * SK + k0;
#pragma unroll
        for (int rb = 0; rb < 4; ++rb)
            c4[nf][rb] = (*(const f32x4*)&bpr[rb * 16] +
                          *(const f32x4*)&npr[rb * 16]) * LOG2E - MFIX;
    }
}

__global__ __launch_bounds__(256, 1)
void attn_kernel(const u16* __restrict__ Qb, const u16* __restrict__ Kb,
                 const u16* __restrict__ vT, const u16* __restrict__ gateb,
                 const float* __restrict__ bias, const float* __restrict__ nbias,
                 u16* __restrict__ wavg)
{
    const int tid = threadIdx.x, lane = tid & 63, wv = tid >> 6;
    const int lr = lane & 15, lg = lane >> 4;
    const int bid = blockIdx.x;
    const int swz = (bid & 7) * 192 + (bid >> 3);
    const int unit = swz * 4 + wv;            // b*48 + qt*8 + h
    const int b = unit / 48;
    const int rem = unit - b * 48;
    const int q0 = (rem >> 3) * 64;
    const int h = rem & 7;

    // Q fragments (B-operand): q = q0+nf*16+lr, c = h*32 + {4lg+j, 16+4lg+j}
    BF8 qf[4];
    {
        const u16* qp = Qb + (size_t)(b * SQ + q0 + lr) * DM + h * 32 + 4 * lg;
#pragma unroll
        for (int nf = 0; nf < 4; ++nf) {
            qf[nf].u2[0] = *(const uint2*)&qp[nf * 16 * DM];
            qf[nf].u2[1] = *(const uint2*)&qp[nf * 16 * DM + 16];
        }
    }

    f32x4 Oacc[2][4];
    float lsum[4];
#pragma unroll
    for (int nf = 0; nf < 4; ++nf) {
        lsum[nf] = 0.f;
        Oacc[0][nf] = (f32x4){0.f, 0.f, 0.f, 0.f};
        Oacc[1][nf] = (f32x4){0.f, 0.f, 0.f, 0.f};
    }

    const u16* kp = Kb + (size_t)(b * SK + lr) * DM + h * 32 + 4 * lg;
    const u16* vp = vT + (size_t)(b * DM + h * 32 + lr) * SK + 4 * lg;
    const float* bp = bias + (size_t)(b * SQ + q0) * SK + 4 * lg;
    const float* np = nbias + ((size_t)h * SQ + q0) * SK + 4 * lg;

    // prologue: tile 0 fully prefetched
    BF8 kf[4], vf[2][2];
    f32x4 c4[4][4];
    load_k4(kp, 0, kf);
    load_v4(vp, 0, vf);
    load_c4(bp, np, 0, lr, c4);

#pragma unroll 1
    for (int kb = 0; kb < 6; ++kb) {
        const int k0 = kb * 64;

        // 1. QK: S^T = K @ Q^T + C  (kf and c4 die here)
        f32x4 st[4][4];
#pragma unroll
        for (int nf = 0; nf < 4; ++nf)
#pragma unroll
            for (int rb = 0; rb < 4; ++rb)
                st[nf][rb] = __builtin_amdgcn_mfma_f32_16x16x32_bf16(
                    kf[rb].v8, qf[nf].v8, c4[nf][rb], 0, 0, 0);

        // 2. issue ALL next-tile loads into freed registers; latency hides
        //    under exp2 + PV below
        BF8 kfn[4], vfn[2][2];
        f32x4 c4n[4][4];
        if (kb < 5) {
            load_k4(kp, k0 + 64, kfn);
            load_v4(vp, k0 + 64, vfn);
            load_c4(bp, np, k0 + 64, lr, c4n);
        }

        // 3. p = exp2(st); per-lane l partials; pack bf16 (no cross-lane)
        BF8 pvv[2][4];
#pragma unroll
        for (int nf = 0; nf < 4; ++nf)
#pragma unroll
            for (int rb = 0; rb < 4; ++rb) {
                f32x4 e;
                e[0] = __builtin_amdgcn_exp2f(st[nf][rb][0]);
                e[1] = __builtin_amdgcn_exp2f(st[nf][rb][1]);
                e[2] = __builtin_amdgcn_exp2f(st[nf][rb][2]);
                e[3] = __builtin_amdgcn_exp2f(st[nf][rb][3]);
                lsum[nf] += (e[0] + e[1]) + (e[2] + e[3]);
                pvv[rb >> 1][nf].u2[rb & 1] = pack4c(e);
            }

        // 4. O^T += V^T @ P^T (vf dies here)
#pragma unroll
        for (int kc = 0; kc < 2; ++kc)
#pragma unroll
            for (int cf = 0; cf < 2; ++cf)
#pragma unroll
                for (int nf = 0; nf < 4; ++nf)
                    Oacc[cf][nf] = __builtin_amdgcn_mfma_f32_16x16x32_bf16(
                        vf[kc][cf].v8, pvv[kc][nf].v8, Oacc[cf][nf], 0, 0, 0);

        // 5. swap
        if (kb < 5) {
#pragma unroll
            for (int rb = 0; rb < 4; ++rb) kf[rb] = kfn[rb];
#pragma unroll
            for (int kc = 0; kc < 2; ++kc)
#pragma unroll
                for (int cf = 0; cf < 2; ++cf) vf[kc][cf] = vfn[kc][cf];
#pragma unroll
            for (int nf = 0; nf < 4; ++nf)
#pragma unroll
                for (int rb = 0; rb < 4; ++rb) c4[nf][rb] = c4n[nf][rb];
        }
    }

    // l: reduce across the 4 lg lane-groups (only cross-lane ops in kernel)
#pragma unroll
    for (int nf = 0; nf < 4; ++nf) {
        lsum[nf] += __shfl_xor(lsum[nf], 16, 64);
        lsum[nf] += __shfl_xor(lsum[nf], 32, 64);
    }

    // epilogue: O^T D-layout: row = c-local = cf*16+4lg+r, col = q = nf*16+lr
#pragma unroll
    for (int nf = 0; nf < 4; ++nf) {
        float rl = 1.0f / lsum[nf];
        size_t qrow = (size_t)(b * SQ + q0 + nf * 16 + lr);
#pragma unroll
        for (int cf = 0; cf < 2; ++cf) {
            size_t idx = qrow * DM + h * 32 + cf * 16 + 4 * lg;
            uint2 g2 = *(const uint2*)&gateb[idx];
            float g0 = bf2f((u16)(g2.x & 0xffff)), g1 = bf2f((u16)(g2.x >> 16));
            float g2f = bf2f((u16)(g2.y & 0xffff)), g3 = bf2f((u16)(g2.y >> 16));
            f32x4 o = Oacc[cf][nf];
            *(uint2*)&wavg[idx] = pack4(o[0] * rl * g0, o[1] * rl * g1,
                                        o[2] * rl * g2f, o[3] * rl * g3);
        }
    }
}

// ---------------------------------------------------------------------------
extern "C" void kernel_launch(void* const* d_in, const int* in_sizes, int n_in,
                              void* d_out, int out_size, void* d_ws, size_t ws_size,
                              hipStream_t stream) {
    const float* q_data = (const float*)d_in[0];
    const float* m_data = (const float*)d_in[1];
    const float* bias   = (const float*)d_in[2];
    const float* nbias  = (const float*)d_in[3];
    const float* q_w    = (const float*)d_in[4];
    const float* k_w    = (const float*)d_in[5];
    const float* v_w    = (const float*)d_in[6];
    const float* o_w    = (const float*)d_in[7];
    const float* o_b    = (const float*)d_in[8];
    const float* g_w    = (const float*)d_in[9];
    const float* g_b    = (const float*)d_in[10];
    float* out = (float*)d_out;

    const size_t MB = (size_t)NB * SQ * DM * 2;   // 25165824 bytes per bf16 buffer
    char* ws = (char*)d_ws;
    u16* qb    = (u16*)(ws);
    u16* kb    = (u16*)(ws + MB);
    u16* vTb   = (u16*)(ws + 2 * MB);
    u16* gateb = (u16*)(ws + 3 * MB);
    u16* wavg  = (u16*)(ws + 4 * MB);
    u16* wt    = (u16*)(ws + 5 * MB);             // 5 x 128KB
    u16* Wtq = wt, *Wtk = wt + 65536, *Wtv = wt + 2 * 65536,
       *Wtg = wt + 3 * 65536, *Wto = wt + 4 * 65536;

    prep_w<<<dim3(4, 4, 5), 256, 0, stream>>>(q_w, k_w, v_w, g_w, o_w, wt);
    proj_kernel<0><<<768, 256, 0, stream>>>(q_data, nullptr, Wtq, Wtg, g_b, nullptr,
                                            qb, gateb, nullptr, nullptr);
    proj_kernel<1><<<768, 256, 0, stream>>>(m_data, nullptr, Wtk, Wtv, nullptr, nullptr,
                                            kb, nullptr, vTb, nullptr);

    attn_kernel<<<1536, 256, 0, stream>>>(qb, kb, vTb, gateb, bias, nbias, wavg);

    proj_kernel<2><<<768, 256, 0, stream>>>(nullptr, wavg, Wto, nullptr, nullptr, o_b,
                                            nullptr, nullptr, nullptr, out);
}

// Round 11
// 291.348 us; speedup vs baseline: 1.5243x; 1.5243x over previous
//
#include <hip/hip_runtime.h>
#include <hip/hip_bf16.h>

#define DM 256
#define NB 128
#define SQ 384
#define SK 384

typedef __bf16 bf16x4 __attribute__((ext_vector_type(4)));
typedef __bf16 bf16x8 __attribute__((ext_vector_type(8)));
typedef float f32x4 __attribute__((ext_vector_type(4)));
typedef unsigned short u16;
typedef unsigned int u32;

union BF8 { bf16x8 v8; bf16x4 v4[2]; uint2 u2[2]; };

__device__ __forceinline__ u16 f2bf(float f) {
    union { float fv; u32 u; } v; v.fv = f;
    u32 r = v.u + 0x7FFFu + ((v.u >> 16) & 1u);
    return (u16)(r >> 16);
}
__device__ __forceinline__ float bf2f(u16 u) {
    union { u32 v; float f; } x; x.v = ((u32)u) << 16; return x.f;
}
__device__ __forceinline__ uint2 pack4(float a, float b, float c, float d) {
    uint2 r;
    r.x = (u32)f2bf(a) | ((u32)f2bf(b) << 16);
    r.y = (u32)f2bf(c) | ((u32)f2bf(d) << 16);
    return r;
}
__device__ __forceinline__ uint2 pack4c(f32x4 v) {
    bf16x4 t;
    t[0] = (__bf16)v[0]; t[1] = (__bf16)v[1];
    t[2] = (__bf16)v[2]; t[3] = (__bf16)v[3];
    union { bf16x4 b; uint2 u; } cv; cv.b = t; return cv.u;
}

// ---------------------------------------------------------------------------
// prep_w: W[k][n] fp32 -> Wt[n][k] bf16. q_w gets scale*log2(e) folded.
// ---------------------------------------------------------------------------
__global__ __launch_bounds__(256)
void prep_w(const float* __restrict__ q_w, const float* __restrict__ k_w,
            const float* __restrict__ v_w, const float* __restrict__ g_w,
            const float* __restrict__ o_w, u16* __restrict__ wt)
{
    __shared__ float t[64][65];
    const int mat = blockIdx.z;
    const float* src = mat == 0 ? q_w : mat == 1 ? k_w : mat == 2 ? v_w : mat == 3 ? g_w : o_w;
    const float scale = (mat == 0) ? (float)(0.17677669529663687 * 1.4426950408889634) : 1.0f;
    const int k0 = blockIdx.x * 64, n0 = blockIdx.y * 64;
    const int tid = threadIdx.x;
#pragma unroll
    for (int i = 0; i < 4; ++i) {
        int pos = tid + i * 256;
        int r = pos >> 4, c4 = (pos & 15) * 4;
        f32x4 v = *(const f32x4*)&src[(size_t)(k0 + r) * DM + n0 + c4];
        t[r][c4 + 0] = v[0]; t[r][c4 + 1] = v[1]; t[r][c4 + 2] = v[2]; t[r][c4 + 3] = v[3];
    }
    __syncthreads();
    const int nr = tid >> 2, kq = (tid & 3) * 16;
    u16* dst = wt + (size_t)mat * DM * DM + (size_t)(n0 + nr) * DM + k0 + kq;
#pragma unroll
    for (int j = 0; j < 16; j += 4) {
        uint2 p = pack4(t[kq + j][nr] * scale, t[kq + j + 1][nr] * scale,
                        t[kq + j + 2][nr] * scale, t[kq + j + 3][nr] * scale);
        *(uint2*)&dst[j] = p;
    }
}

// ---------------------------------------------------------------------------
// proj_kernel (unchanged from R9)
// ---------------------------------------------------------------------------
template<int MODE>
__global__ __launch_bounds__(256)
void proj_kernel(const float* __restrict__ Af, const u16* __restrict__ Abf,
                 const u16* __restrict__ Wt1, const u16* __restrict__ Wt2,
                 const float* __restrict__ gb, const float* __restrict__ ob,
                 u16* __restrict__ out1, u16* __restrict__ gate,
                 u16* __restrict__ vT, float* __restrict__ outf)
{
    __shared__ u16 Wlds[64 * 256];
    const int tid = threadIdx.x, lane = tid & 63, w = tid >> 6;
    const int lr = lane & 15, lg = lane >> 4;
    const int m0 = blockIdx.x * 64;

    BF8 af[8];
    if (MODE <= 1) {
        const float* arow = Af + (size_t)(m0 + w * 16 + lr) * DM + 4 * lg;
#pragma unroll
        for (int ks = 0; ks < 8; ++ks) {
            f32x4 v0 = *(const f32x4*)&arow[ks * 32];
            f32x4 v1 = *(const f32x4*)&arow[ks * 32 + 16];
            af[ks].u2[0] = pack4(v0[0], v0[1], v0[2], v0[3]);
            af[ks].u2[1] = pack4(v1[0], v1[1], v1[2], v1[3]);
        }
    } else {
        const u16* arow = Abf + (size_t)(m0 + w * 16 + lr) * DM + 4 * lg;
#pragma unroll
        for (int ks = 0; ks < 8; ++ks) {
            af[ks].u2[0] = *(const uint2*)&arow[ks * 32];
            af[ks].u2[1] = *(const uint2*)&arow[ks * 32 + 16];
        }
    }

    const int NSLAB = (MODE == 2) ? 4 : 8;
    for (int sl = 0; sl < NSLAB; ++sl) {
        const u16* Wsrc = (sl < 4) ? Wt1 : Wt2;
        const int n0 = (sl & 3) * 64;
        if (sl) __syncthreads();
#pragma unroll
        for (int i = 0; i < 8; ++i) {
            int pos = tid + i * 256;
            int nr = pos >> 5, c8 = (pos & 31) * 8;
            uint4 gv = *(const uint4*)&Wsrc[(size_t)(n0 + nr) * DM + c8];
            int within = c8 & 31;
            int pa2 = (c8 >> 5) * 64 + ((within >> 3) & 1) * 32 + (within >> 4) * 8;
            int sw = (nr & 7) << 4;
            char* rb_ = (char*)Wlds + nr * 512;
            *(uint2*)(rb_ + (pa2 ^ sw)) = make_uint2(gv.x, gv.y);
            *(uint2*)(rb_ + ((pa2 + 16) ^ sw)) = make_uint2(gv.z, gv.w);
        }
        __syncthreads();

        f32x4 acc[4];
#pragma unroll
        for (int nf = 0; nf < 4; ++nf) acc[nf] = (f32x4){0.f, 0.f, 0.f, 0.f};
#pragma unroll
        for (int ks = 0; ks < 8; ++ks) {
#pragma unroll
            for (int nf = 0; nf < 4; ++nf) {
                int row = nf * 16 + lr;
                bf16x8 bfr = *(const bf16x8*)((char*)Wlds + row * 512 +
                                              ((ks * 64 + lg * 16) ^ ((row & 7) << 4)));
                acc[nf] = __builtin_amdgcn_mfma_f32_16x16x32_bf16(af[ks].v8, bfr, acc[nf], 0, 0, 0);
            }
        }

#pragma unroll
        for (int nf = 0; nf < 4; ++nf) {
            int n = n0 + nf * 16 + lr;
            int gn = (sl & 3) * 64 + nf * 16 + lr;
            if (MODE == 0) {
                if (sl < 4) {
#pragma unroll
                    for (int r = 0; r < 4; ++r)
                        out1[(size_t)(m0 + w * 16 + 4 * lg + r) * DM + n] = f2bf(acc[nf][r]);
                } else {
                    float gbv = gb[gn];
#pragma unroll
                    for (int r = 0; r < 4; ++r)
                        gate[(size_t)(m0 + w * 16 + 4 * lg + r) * DM + gn] =
                            f2bf(1.f / (1.f + __expf(-(acc[nf][r] + gbv))));
                }
            } else if (MODE == 1) {
                if (sl < 4) {
#pragma unroll
                    for (int r = 0; r < 4; ++r)
                        out1[(size_t)(m0 + w * 16 + 4 * lg + r) * DM + n] = f2bf(acc[nf][r]);
                } else {
                    int bb = m0 / SQ;
                    int kkl = m0 - bb * SQ + w * 16 + 4 * lg;
                    *(uint2*)&vT[(size_t)(bb * DM + gn) * SK + kkl] =
                        pack4(acc[nf][0], acc[nf][1], acc[nf][2], acc[nf][3]);
                }
            } else {
                float obv = ob[n];
#pragma unroll
                for (int r = 0; r < 4; ++r)
                    outf[(size_t)(m0 + w * 16 + 4 * lg + r) * DM + n] = acc[nf][r] + obv;
            }
        }
    }
}

// ---------------------------------------------------------------------------
// attn R11: 512 thr = 8 waves = 8 heads, block=(qt,b), qt-major grid so all
// XCDs share one qt stripe -> nbias (786KB/XCD) is L2-hot. K/V/bias tiles
// (KVBLK=32) staged in DOUBLE-BUFFERED LDS (40KB x2) via async-split: each
// thread issues 5 independent global loads for tile t+1 BEFORE computing
// tile t, commits to LDS after compute, one barrier per tile -> blockwide
// MLP instead of the serialized per-wave loads of R6-R10. Fixed-max exp2
// softmax (R8), deferred lsum. launch_bounds(512,1): 256-VGPR budget, no
// spill possible (the R4/R6/R8 failure mode).
// ---------------------------------------------------------------------------
__global__ __launch_bounds__(512, 1)
void attn_kernel(const u16* __restrict__ Qb, const u16* __restrict__ Kb,
                 const u16* __restrict__ vT, const u16* __restrict__ gateb,
                 const float* __restrict__ bias, const float* __restrict__ nbias,
                 u16* __restrict__ wavg)
{
    extern __shared__ char smem[];
    // buffer i at smem + i*40960: K 16KB | V 16KB | bias 8KB
    const int tid = threadIdx.x, lane = tid & 63, h = tid >> 6;
    const int lr = lane & 15, lg = lane >> 4;
    const int bid = blockIdx.x;
    const int qt = bid >> 7, b = bid & 127;   // qt-major: XCDs round-robin b
    const int q0 = qt * 64;
    const float LOG2E = 1.4426950408889634f;
    const float MFIX = 20.0f;

    // staging geometry (fixed per thread)
    const int krow = tid >> 5, kc8 = (tid & 31) * 8;          // K: rows krow, krow+16
    const int vrow = tid >> 2, vg = tid & 3;                  // V: rows vrow, vrow+128
    const int bq = tid >> 3, bch = tid & 7;                   // bias: 1 chunk
    const int kwithin = kc8 & 31;
    const int kpa2 = (kc8 >> 5) * 64 + ((kwithin >> 3) & 1) * 32 + (kwithin >> 4) * 8;
    const int ksw = (krow & 7) << 4;
    const int vpA = (2 * vg) & 3, vpB = (2 * vg + 1) & 3, vhi = (vg >> 1) * 8;
    const int vsw = vrow & 3;

    uint4 skr0, skr1, svr0, svr1; f32x4 sbr;
    auto stage_issue = [&](int k0n) {
        skr0 = *(const uint4*)&Kb[((size_t)b * SK + k0n + krow) * DM + kc8];
        skr1 = *(const uint4*)&Kb[((size_t)b * SK + k0n + krow + 16) * DM + kc8];
        svr0 = *(const uint4*)&vT[((size_t)b * DM + vrow) * SK + k0n + vg * 8];
        svr1 = *(const uint4*)&vT[((size_t)b * DM + vrow + 128) * SK + k0n + vg * 8];
        sbr  = *(const f32x4*)&bias[((size_t)b * SQ + q0 + bq) * SK + k0n + bch * 4];
    };
    auto stage_commit = [&](char* buf) {
        char* Kb_ = buf;            // 16KB
        char* Vb_ = buf + 16384;    // 16KB
        char* Bb_ = buf + 32768;    // 8KB
        char* r0 = Kb_ + krow * 512;
        *(uint2*)(r0 + (kpa2 ^ ksw)) = make_uint2(skr0.x, skr0.y);
        *(uint2*)(r0 + ((kpa2 + 16) ^ ksw)) = make_uint2(skr0.z, skr0.w);
        char* r1 = Kb_ + (krow + 16) * 512;
        *(uint2*)(r1 + (kpa2 ^ ksw)) = make_uint2(skr1.x, skr1.y);
        *(uint2*)(r1 + ((kpa2 + 16) ^ ksw)) = make_uint2(skr1.z, skr1.w);
        char* v0 = Vb_ + vrow * 64;
        *(uint2*)(v0 + (((vpA ^ vsw) << 4) + vhi)) = make_uint2(svr0.x, svr0.y);
        *(uint2*)(v0 + (((vpB ^ vsw) << 4) + vhi)) = make_uint2(svr0.z, svr0.w);
        char* v1 = Vb_ + (vrow + 128) * 64;
        *(uint2*)(v1 + (((vpA ^ vsw) << 4) + vhi)) = make_uint2(svr1.x, svr1.y);
        *(uint2*)(v1 + (((vpB ^ vsw) << 4) + vhi)) = make_uint2(svr1.z, svr1.w);
        f32x4 sb = sbr * LOG2E - MFIX;
        *(f32x4*)(Bb_ + bq * 128 + ((bch ^ (bq & 7)) << 4)) = sb;
    };

    // Q fragments (B-operand), pre-scaled by scale*log2e in prep_w
    BF8 qf[4];
    {
        const u16* qp = Qb + (size_t)(b * SQ + q0 + lr) * DM + h * 32 + 4 * lg;
#pragma unroll
        for (int nf = 0; nf < 4; ++nf) {
            qf[nf].u2[0] = *(const uint2*)&qp[nf * 16 * DM];
            qf[nf].u2[1] = *(const uint2*)&qp[nf * 16 * DM + 16];
        }
    }

    f32x4 Oacc[2][4];
    float lsum[4];
#pragma unroll
    for (int nf = 0; nf < 4; ++nf) {
        lsum[nf] = 0.f;
        Oacc[0][nf] = (f32x4){0.f, 0.f, 0.f, 0.f};
        Oacc[1][nf] = (f32x4){0.f, 0.f, 0.f, 0.f};
    }

    const float* np = nbias + ((size_t)h * SQ + q0) * SK + 4 * lg;

    // prologue: tile 0 staged synchronously
    stage_issue(0);
    stage_commit(smem);
    __syncthreads();

    int cur = 0;
#pragma unroll 1
    for (int kb = 0; kb < 12; ++kb) {
        const int k0 = kb * 32;
        if (kb < 11) stage_issue(k0 + 32);     // async: in flight during compute

        char* buf = smem + cur * 40960;
        char* Kc = buf, *Vc = buf + 16384, *Bc = buf + 32768;

        // nbias batch (L2-hot by qt-major grid)
        f32x4 n4r[4][2];
#pragma unroll
        for (int nf = 0; nf < 4; ++nf)
#pragma unroll
            for (int rb = 0; rb < 2; ++rb)
                n4r[nf][rb] = *(const f32x4*)&np[(size_t)(nf * 16 + lr) * SK + k0 + rb * 16];

        // QK: S^T = K @ Q^T + (bias_lds + nbias*log2e)
        f32x4 st[4][2];
#pragma unroll
        for (int nf = 0; nf < 4; ++nf)
#pragma unroll
            for (int rb = 0; rb < 2; ++rb) {
                f32x4 b4 = *(const f32x4*)(Bc + (nf * 16 + lr) * 128 +
                                           (((rb * 4 + lg) ^ (lr & 7)) << 4));
                f32x4 c4 = n4r[nf][rb] * LOG2E + b4;
                bf16x8 kfr = *(const bf16x8*)(Kc + (rb * 16 + lr) * 512 +
                                              ((h * 64 + lg * 16) ^ ((lr & 7) << 4)));
                st[nf][rb] = __builtin_amdgcn_mfma_f32_16x16x32_bf16(kfr, qf[nf].v8, c4, 0, 0, 0);
            }

        // exp2, pack, per-lane lsum
        BF8 pvv[4];
#pragma unroll
        for (int nf = 0; nf < 4; ++nf)
#pragma unroll
            for (int rb = 0; rb < 2; ++rb) {
                f32x4 e;
                e[0] = __builtin_amdgcn_exp2f(st[nf][rb][0]);
                e[1] = __builtin_amdgcn_exp2f(st[nf][rb][1]);
                e[2] = __builtin_amdgcn_exp2f(st[nf][rb][2]);
                e[3] = __builtin_amdgcn_exp2f(st[nf][rb][3]);
                lsum[nf] += (e[0] + e[1]) + (e[2] + e[3]);
                pvv[nf].u2[rb] = pack4c(e);
            }

        // PV: O^T += V^T @ P^T
#pragma unroll
        for (int cf = 0; cf < 2; ++cf) {
            bf16x8 vfr = *(const bf16x8*)(Vc + (h * 32 + cf * 16 + lr) * 64 +
                                          ((lg ^ (lr & 3)) << 4));
#pragma unroll
            for (int nf = 0; nf < 4; ++nf)
                Oacc[cf][nf] = __builtin_amdgcn_mfma_f32_16x16x32_bf16(
                    vfr, pvv[nf].v8, Oacc[cf][nf], 0, 0, 0);
        }

        if (kb < 11) {
            stage_commit(smem + (cur ^ 1) * 40960);  // waits loads, writes LDS
            __syncthreads();
        }
        cur ^= 1;
    }

    // l reduction (only cross-lane ops in kernel)
#pragma unroll
    for (int nf = 0; nf < 4; ++nf) {
        lsum[nf] += __shfl_xor(lsum[nf], 16, 64);
        lsum[nf] += __shfl_xor(lsum[nf], 32, 64);
    }

    // epilogue
#pragma unroll
    for (int nf = 0; nf < 4; ++nf) {
        float rl = 1.0f / lsum[nf];
        size_t qrow = (size_t)(b * SQ + q0 + nf * 16 + lr);
#pragma unroll
        for (int cf = 0; cf < 2; ++cf) {
            size_t idx = qrow * DM + h * 32 + cf * 16 + 4 * lg;
            uint2 g2 = *(const uint2*)&gateb[idx];
            float g0 = bf2f((u16)(g2.x & 0xffff)), g1 = bf2f((u16)(g2.x >> 16));
            float g2f = bf2f((u16)(g2.y & 0xffff)), g3 = bf2f((u16)(g2.y >> 16));
            f32x4 o = Oacc[cf][nf];
            *(uint2*)&wavg[idx] = pack4(o[0] * rl * g0, o[1] * rl * g1,
                                        o[2] * rl * g2f, o[3] * rl * g3);
        }
    }
}

// ---------------------------------------------------------------------------
extern "C" void kernel_launch(void* const* d_in, const int* in_sizes, int n_in,
                              void* d_out, int out_size, void* d_ws, size_t ws_size,
                              hipStream_t stream) {
    const float* q_data = (const float*)d_in[0];
    const float* m_data = (const float*)d_in[1];
    const float* bias   = (const float*)d_in[2];
    const float* nbias  = (const float*)d_in[3];
    const float* q_w    = (const float*)d_in[4];
    const float* k_w    = (const float*)d_in[5];
    const float* v_w    = (const float*)d_in[6];
    const float* o_w    = (const float*)d_in[7];
    const float* o_b    = (const float*)d_in[8];
    const float* g_w    = (const float*)d_in[9];
    const float* g_b    = (const float*)d_in[10];
    float* out = (float*)d_out;

    const size_t MB = (size_t)NB * SQ * DM * 2;
    char* ws = (char*)d_ws;
    u16* qb    = (u16*)(ws);
    u16* kb    = (u16*)(ws + MB);
    u16* vTb   = (u16*)(ws + 2 * MB);
    u16* gateb = (u16*)(ws + 3 * MB);
    u16* wavg  = (u16*)(ws + 4 * MB);
    u16* wt    = (u16*)(ws + 5 * MB);
    u16* Wtq = wt, *Wtk = wt + 65536, *Wtv = wt + 2 * 65536,
       *Wtg = wt + 3 * 65536, *Wto = wt + 4 * 65536;

    prep_w<<<dim3(4, 4, 5), 256, 0, stream>>>(q_w, k_w, v_w, g_w, o_w, wt);
    proj_kernel<0><<<768, 256, 0, stream>>>(q_data, nullptr, Wtq, Wtg, g_b, nullptr,
                                            qb, gateb, nullptr, nullptr);
    proj_kernel<1><<<768, 256, 0, stream>>>(m_data, nullptr, Wtk, Wtv, nullptr, nullptr,
                                            kb, nullptr, vTb, nullptr);

    const int ATTN_SMEM = 2 * 40960;  // 80 KB
    hipFuncSetAttribute((const void*)attn_kernel,
                        hipFuncAttributeMaxDynamicSharedMemorySize, ATTN_SMEM);
    attn_kernel<<<768, 512, ATTN_SMEM, stream>>>(qb, kb, vTb, gateb, bias, nbias, wavg);

    proj_kernel<2><<<768, 256, 0, stream>>>(nullptr, wavg, Wto, nullptr, nullptr, o_b,
                                            nullptr, nullptr, nullptr, out);
}

// Round 12
// 282.925 us; speedup vs baseline: 1.5697x; 1.0298x over previous
//
#include <hip/hip_runtime.h>
#include <hip/hip_bf16.h>

#define DM 256
#define NB 128
#define SQ 384
#define SK 384

typedef __bf16 bf16x4 __attribute__((ext_vector_type(4)));
typedef __bf16 bf16x8 __attribute__((ext_vector_type(8)));
typedef float f32x4 __attribute__((ext_vector_type(4)));
typedef unsigned short u16;
typedef unsigned int u32;

union BF8 { bf16x8 v8; bf16x4 v4[2]; uint2 u2[2]; };

__device__ __forceinline__ u16 f2bf(float f) {
    union { float fv; u32 u; } v; v.fv = f;
    u32 r = v.u + 0x7FFFu + ((v.u >> 16) & 1u);
    return (u16)(r >> 16);
}
__device__ __forceinline__ float bf2f(u16 u) {
    union { u32 v; float f; } x; x.v = ((u32)u) << 16; return x.f;
}
__device__ __forceinline__ uint2 pack4(float a, float b, float c, float d) {
    uint2 r;
    r.x = (u32)f2bf(a) | ((u32)f2bf(b) << 16);
    r.y = (u32)f2bf(c) | ((u32)f2bf(d) << 16);
    return r;
}
__device__ __forceinline__ uint2 pack4c(f32x4 v) {
    bf16x4 t;
    t[0] = (__bf16)v[0]; t[1] = (__bf16)v[1];
    t[2] = (__bf16)v[2]; t[3] = (__bf16)v[3];
    union { bf16x4 b; uint2 u; } cv; cv.b = t; return cv.u;
}
// async global->LDS, 16B per lane; LDS dest = wave-uniform base + lane*16
__device__ __forceinline__ void glds16(const void* g, void* l) {
    __builtin_amdgcn_global_load_lds(
        (const __attribute__((address_space(1))) unsigned int*)g,
        (__attribute__((address_space(3))) unsigned int*)l, 16, 0, 0);
}

// ---------------------------------------------------------------------------
// prep_w: W[k][n] fp32 -> Wt[n][k] bf16. q_w gets scale*log2(e) folded.
// ---------------------------------------------------------------------------
__global__ __launch_bounds__(256)
void prep_w(const float* __restrict__ q_w, const float* __restrict__ k_w,
            const float* __restrict__ v_w, const float* __restrict__ g_w,
            const float* __restrict__ o_w, u16* __restrict__ wt)
{
    __shared__ float t[64][65];
    const int mat = blockIdx.z;
    const float* src = mat == 0 ? q_w : mat == 1 ? k_w : mat == 2 ? v_w : mat == 3 ? g_w : o_w;
    const float scale = (mat == 0) ? (float)(0.17677669529663687 * 1.4426950408889634) : 1.0f;
    const int k0 = blockIdx.x * 64, n0 = blockIdx.y * 64;
    const int tid = threadIdx.x;
#pragma unroll
    for (int i = 0; i < 4; ++i) {
        int pos = tid + i * 256;
        int r = pos >> 4, c4 = (pos & 15) * 4;
        f32x4 v = *(const f32x4*)&src[(size_t)(k0 + r) * DM + n0 + c4];
        t[r][c4 + 0] = v[0]; t[r][c4 + 1] = v[1]; t[r][c4 + 2] = v[2]; t[r][c4 + 3] = v[3];
    }
    __syncthreads();
    const int nr = tid >> 2, kq = (tid & 3) * 16;
    u16* dst = wt + (size_t)mat * DM * DM + (size_t)(n0 + nr) * DM + k0 + kq;
#pragma unroll
    for (int j = 0; j < 16; j += 4) {
        uint2 p = pack4(t[kq + j][nr] * scale, t[kq + j + 1][nr] * scale,
                        t[kq + j + 2][nr] * scale, t[kq + j + 3][nr] * scale);
        *(uint2*)&dst[j] = p;
    }
}

// ---------------------------------------------------------------------------
// prep_nb: nb2 = nbias * log2e - MFIX (fp32), so attn's C-operand is one fma.
// ---------------------------------------------------------------------------
__global__ __launch_bounds__(256)
void prep_nb(const float* __restrict__ nb, float* __restrict__ nb2)
{
    int i = (blockIdx.x * 256 + threadIdx.x) * 4;
    f32x4 v = *(const f32x4*)&nb[i];
    *(f32x4*)&nb2[i] = v * 1.4426950408889634f - 20.0f;
}

// ---------------------------------------------------------------------------
// proj_kernel: out = A[M,256] @ W[256,256] (+epilogue).
// MODE 1 epilogue PERMUTES kb columns and vT k-positions by
// pi(cc) = ((cc>>2)&3)*8 + ((cc>>4)&1)*4 + (cc&3)  (per 32-block)
// so each MFMA fragment's {4g..4g+3, 16+4g..16+4g+3} elements become 16B
// contiguous in global memory -> stageable by global_load_lds width 16.
// ---------------------------------------------------------------------------
template<int MODE>
__global__ __launch_bounds__(256)
void proj_kernel(const float* __restrict__ Af, const u16* __restrict__ Abf,
                 const u16* __restrict__ Wt1, const u16* __restrict__ Wt2,
                 const float* __restrict__ gb, const float* __restrict__ ob,
                 u16* __restrict__ out1, u16* __restrict__ gate,
                 u16* __restrict__ vT, float* __restrict__ outf)
{
    __shared__ u16 Wlds[64 * 256];
    const int tid = threadIdx.x, lane = tid & 63, w = tid >> 6;
    const int lr = lane & 15, lg = lane >> 4;
    const int m0 = blockIdx.x * 64;

    BF8 af[8];
    if (MODE <= 1) {
        const float* arow = Af + (size_t)(m0 + w * 16 + lr) * DM + 4 * lg;
#pragma unroll
        for (int ks = 0; ks < 8; ++ks) {
            f32x4 v0 = *(const f32x4*)&arow[ks * 32];
            f32x4 v1 = *(const f32x4*)&arow[ks * 32 + 16];
            af[ks].u2[0] = pack4(v0[0], v0[1], v0[2], v0[3]);
            af[ks].u2[1] = pack4(v1[0], v1[1], v1[2], v1[3]);
        }
    } else {
        const u16* arow = Abf + (size_t)(m0 + w * 16 + lr) * DM + 4 * lg;
#pragma unroll
        for (int ks = 0; ks < 8; ++ks) {
            af[ks].u2[0] = *(const uint2*)&arow[ks * 32];
            af[ks].u2[1] = *(const uint2*)&arow[ks * 32 + 16];
        }
    }

    const int NSLAB = (MODE == 2) ? 4 : 8;
    for (int sl = 0; sl < NSLAB; ++sl) {
        const u16* Wsrc = (sl < 4) ? Wt1 : Wt2;
        const int n0 = (sl & 3) * 64;
        if (sl) __syncthreads();
#pragma unroll
        for (int i = 0; i < 8; ++i) {
            int pos = tid + i * 256;
            int nr = pos >> 5, c8 = (pos & 31) * 8;
            uint4 gv = *(const uint4*)&Wsrc[(size_t)(n0 + nr) * DM + c8];
            int within = c8 & 31;
            int pa2 = (c8 >> 5) * 64 + ((within >> 3) & 1) * 32 + (within >> 4) * 8;
            int sw = (nr & 7) << 4;
            char* rb_ = (char*)Wlds + nr * 512;
            *(uint2*)(rb_ + (pa2 ^ sw)) = make_uint2(gv.x, gv.y);
            *(uint2*)(rb_ + ((pa2 + 16) ^ sw)) = make_uint2(gv.z, gv.w);
        }
        __syncthreads();

        f32x4 acc[4];
#pragma unroll
        for (int nf = 0; nf < 4; ++nf) acc[nf] = (f32x4){0.f, 0.f, 0.f, 0.f};
#pragma unroll
        for (int ks = 0; ks < 8; ++ks) {
#pragma unroll
            for (int nf = 0; nf < 4; ++nf) {
                int row = nf * 16 + lr;
                bf16x8 bfr = *(const bf16x8*)((char*)Wlds + row * 512 +
                                              ((ks * 64 + lg * 16) ^ ((row & 7) << 4)));
                acc[nf] = __builtin_amdgcn_mfma_f32_16x16x32_bf16(af[ks].v8, bfr, acc[nf], 0, 0, 0);
            }
        }

#pragma unroll
        for (int nf = 0; nf < 4; ++nf) {
            int n = n0 + nf * 16 + lr;
            int gn = (sl & 3) * 64 + nf * 16 + lr;
            if (MODE == 0) {
                if (sl < 4) {
#pragma unroll
                    for (int r = 0; r < 4; ++r)
                        out1[(size_t)(m0 + w * 16 + 4 * lg + r) * DM + n] = f2bf(acc[nf][r]);
                } else {
                    float gbv = gb[gn];
#pragma unroll
                    for (int r = 0; r < 4; ++r)
                        gate[(size_t)(m0 + w * 16 + 4 * lg + r) * DM + gn] =
                            f2bf(1.f / (1.f + __expf(-(acc[nf][r] + gbv))));
                }
            } else if (MODE == 1) {
                if (sl < 4) {
                    // permuted kb column
                    int pn = (n & ~31) | (((n >> 2) & 3) << 3) | (((n >> 4) & 1) << 2) | (n & 3);
#pragma unroll
                    for (int r = 0; r < 4; ++r)
                        out1[(size_t)(m0 + w * 16 + 4 * lg + r) * DM + pn] = f2bf(acc[nf][r]);
                } else {
                    int bb = m0 / SQ;
                    int kkl = m0 - bb * SQ + w * 16 + 4 * lg;
                    int cc = kkl & 31;
                    int kkp = (kkl & ~31) | (((cc >> 2) & 3) << 3) | (((cc >> 4) & 1) << 2);
                    *(uint2*)&vT[(size_t)(bb * DM + gn) * SK + kkp] =
                        pack4(acc[nf][0], acc[nf][1], acc[nf][2], acc[nf][3]);
                }
            } else {
                float obv = ob[n];
#pragma unroll
                for (int r = 0; r < 4; ++r)
                    outf[(size_t)(m0 + w * 16 + 4 * lg + r) * DM + n] = acc[nf][r] + obv;
            }
        }
    }
}

// ---------------------------------------------------------------------------
// attn R12: 2-phase async pipeline via global_load_lds (T3-lite).
// Per tile each wave issues 5 x 16B-wide global_load_lds (2 K, 2 V, 1 bias)
// for tile t+1, computes tile t from LDS, then vmcnt(0)+barrier. Loads are
// side-effecting -> compiler cannot sink them (R11's register staging was
// sunk to its use, serializing). LDS dest is linear (base+lane*16); the
// bank-conflict swizzle lives in the per-lane SOURCE addresses (inverse XOR)
// + producer-side permutation of kb/vT (see proj MODE 1).
// Layouts per 40KB buffer: K [32k][256c] swz j^(row&7) | V [256c][32k] swz
// j^((row>>1)&3) | bias [64q][32k] f32 swz j^(q&7). All reads 2-way/minimum.
// qt-major grid: nbias slice L2-hot. Fixed-max exp2 softmax (nb2 prescaled).
// ---------------------------------------------------------------------------
__global__ __launch_bounds__(512, 1)
void attn_kernel(const u16* __restrict__ Qb, const u16* __restrict__ Kb,
                 const u16* __restrict__ vT, const u16* __restrict__ gateb,
                 const float* __restrict__ bias, const float* __restrict__ nb2,
                 u16* __restrict__ wavg)
{
    extern __shared__ char smem[];   // 2 x 40960: K 16K | V 16K | bias 8K
    const int tid = threadIdx.x, lane = tid & 63, h = tid >> 6;
    const int lr = lane & 15, lg = lane >> 4;
    const int bid = blockIdx.x;
    const int qt = bid >> 7, b = bid & 127;    // qt-major
    const int q0 = qt * 64;
    const float LOG2E = 1.4426950408889634f;

    // per-lane staging sources (inverse-swizzled). chunk = 16B.
    const int ci0 = (h * 2) * 64 + lane, ci1 = (h * 2 + 1) * 64 + lane;
    const int kr0 = ci0 >> 5, kj0 = (ci0 & 31) ^ (kr0 & 7);
    const int kr1 = ci1 >> 5, kj1 = (ci1 & 31) ^ (kr1 & 7);
    const u16* kg0 = Kb + ((size_t)b * SK + kr0) * DM + kj0 * 8;
    const u16* kg1 = Kb + ((size_t)b * SK + kr1) * DM + kj1 * 8;
    const int vr0 = ci0 >> 2, vj0 = (ci0 & 3) ^ ((vr0 >> 1) & 3);
    const int vr1 = ci1 >> 2, vj1 = (ci1 & 3) ^ ((vr1 >> 1) & 3);
    const u16* vg0 = vT + ((size_t)b * DM + vr0) * SK + vj0 * 8;
    const u16* vg1 = vT + ((size_t)b * DM + vr1) * SK + vj1 * 8;
    const int cib = h * 64 + lane;
    const int bq = cib >> 3, bj = (cib & 7) ^ (bq & 7);
    const float* bg = bias + ((size_t)b * SQ + q0 + bq) * SK + bj * 4;

    // wave-uniform LDS dest offsets
    const int kd0 = (h * 2) * 1024, kd1 = (h * 2 + 1) * 1024;
    const int bd = 32768 + h * 1024;

    // Q fragments (B-operand), pre-scaled by scale*log2e in prep_w
    BF8 qf[4];
    {
        const u16* qp = Qb + (size_t)(b * SQ + q0 + lr) * DM + h * 32 + 4 * lg;
#pragma unroll
        for (int nf = 0; nf < 4; ++nf) {
            qf[nf].u2[0] = *(const uint2*)&qp[nf * 16 * DM];
            qf[nf].u2[1] = *(const uint2*)&qp[nf * 16 * DM + 16];
        }
    }

    f32x4 Oacc[2][4];
    float lsum[4];
#pragma unroll
    for (int nf = 0; nf < 4; ++nf) {
        lsum[nf] = 0.f;
        Oacc[0][nf] = (f32x4){0.f, 0.f, 0.f, 0.f};
        Oacc[1][nf] = (f32x4){0.f, 0.f, 0.f, 0.f};
    }

    const float* np = nb2 + ((size_t)h * SQ + q0) * SK + 4 * lg;

    // prologue: stage tile 0 into buffer 0
    glds16(kg0, smem + kd0); glds16(kg1, smem + kd1);
    glds16(vg0, smem + 16384 + kd0); glds16(vg1, smem + 16384 + kd1);
    glds16(bg, smem + bd);
    kg0 += 32 * DM; kg1 += 32 * DM; vg0 += 32; vg1 += 32; bg += 32;
    asm volatile("s_waitcnt vmcnt(0)" ::: "memory");
    __syncthreads();

    int cur = 0;
#pragma unroll 1
    for (int kb = 0; kb < 12; ++kb) {
        const int k0 = kb * 32;
        if (kb < 11) {   // issue next tile's loads; land under this compute
            char* nbuf = smem + (cur ^ 1) * 40960;
            glds16(kg0, nbuf + kd0); glds16(kg1, nbuf + kd1);
            glds16(vg0, nbuf + 16384 + kd0); glds16(vg1, nbuf + 16384 + kd1);
            glds16(bg, nbuf + bd);
            kg0 += 32 * DM; kg1 += 32 * DM; vg0 += 32; vg1 += 32; bg += 32;
        }
        char* buf = smem + cur * 40960;
        char* Kc = buf; char* Vc = buf + 16384; char* Bc = buf + 32768;

        // QK: S^T = K @ Q^T + (bias*log2e + nb2)
        f32x4 st[4][2];
#pragma unroll
        for (int nf = 0; nf < 4; ++nf)
#pragma unroll
            for (int rb = 0; rb < 2; ++rb) {
                f32x4 n4 = *(const f32x4*)&np[(size_t)(nf * 16 + lr) * SK + k0 + rb * 16];
                f32x4 b4 = *(const f32x4*)(Bc + (nf * 16 + lr) * 128 +
                                           (((rb * 4 + lg) ^ (lr & 7)) << 4));
                f32x4 c4 = b4 * LOG2E + n4;
                bf16x8 kfr = *(const bf16x8*)(Kc + (rb * 16 + lr) * 512 +
                                              (((h * 4 + lg) ^ (lr & 7)) << 4));
                st[nf][rb] = __builtin_amdgcn_mfma_f32_16x16x32_bf16(kfr, qf[nf].v8, c4, 0, 0, 0);
            }

        // exp2, pack, per-lane lsum (no cross-lane ops in loop)
        BF8 pvv[4];
#pragma unroll
        for (int nf = 0; nf < 4; ++nf)
#pragma unroll
            for (int rb = 0; rb < 2; ++rb) {
                f32x4 e;
                e[0] = __builtin_amdgcn_exp2f(st[nf][rb][0]);
                e[1] = __builtin_amdgcn_exp2f(st[nf][rb][1]);
                e[2] = __builtin_amdgcn_exp2f(st[nf][rb][2]);
                e[3] = __builtin_amdgcn_exp2f(st[nf][rb][3]);
                lsum[nf] += (e[0] + e[1]) + (e[2] + e[3]);
                pvv[nf].u2[rb] = pack4c(e);
            }

        // PV: O^T += V^T @ P^T
#pragma unroll
        for (int cf = 0; cf < 2; ++cf) {
            int row = h * 32 + cf * 16 + lr;
            bf16x8 vfr = *(const bf16x8*)(Vc + row * 64 + ((lg ^ ((lr >> 1) & 3)) << 4));
#pragma unroll
            for (int nf = 0; nf < 4; ++nf)
                Oacc[cf][nf] = __builtin_amdgcn_mfma_f32_16x16x32_bf16(
                    vfr, pvv[nf].v8, Oacc[cf][nf], 0, 0, 0);
        }

        if (kb < 11) {
            asm volatile("s_waitcnt vmcnt(0)" ::: "memory");
            __syncthreads();
            cur ^= 1;
        }
    }

    // l reduction (only cross-lane ops in kernel)
#pragma unroll
    for (int nf = 0; nf < 4; ++nf) {
        lsum[nf] += __shfl_xor(lsum[nf], 16, 64);
        lsum[nf] += __shfl_xor(lsum[nf], 32, 64);
    }

    // epilogue: O^T D-layout: row = c-local = cf*16+4lg+r, col = q = nf*16+lr
#pragma unroll
    for (int nf = 0; nf < 4; ++nf) {
        float rl = 1.0f / lsum[nf];
        size_t qrow = (size_t)(b * SQ + q0 + nf * 16 + lr);
#pragma unroll
        for (int cf = 0; cf < 2; ++cf) {
            size_t idx = qrow * DM + h * 32 + cf * 16 + 4 * lg;
            uint2 g2 = *(const uint2*)&gateb[idx];
            float g0 = bf2f((u16)(g2.x & 0xffff)), g1 = bf2f((u16)(g2.x >> 16));
            float g2f = bf2f((u16)(g2.y & 0xffff)), g3 = bf2f((u16)(g2.y >> 16));
            f32x4 o = Oacc[cf][nf];
            *(uint2*)&wavg[idx] = pack4(o[0] * rl * g0, o[1] * rl * g1,
                                        o[2] * rl * g2f, o[3] * rl * g3);
        }
    }
}

// ---------------------------------------------------------------------------
extern "C" void kernel_launch(void* const* d_in, const int* in_sizes, int n_in,
                              void* d_out, int out_size, void* d_ws, size_t ws_size,
                              hipStream_t stream) {
    const float* q_data = (const float*)d_in[0];
    const float* m_data = (const float*)d_in[1];
    const float* bias   = (const float*)d_in[2];
    const float* nbias  = (const float*)d_in[3];
    const float* q_w    = (const float*)d_in[4];
    const float* k_w    = (const float*)d_in[5];
    const float* v_w    = (const float*)d_in[6];
    const float* o_w    = (const float*)d_in[7];
    const float* o_b    = (const float*)d_in[8];
    const float* g_w    = (const float*)d_in[9];
    const float* g_b    = (const float*)d_in[10];
    float* out = (float*)d_out;

    const size_t MB = (size_t)NB * SQ * DM * 2;
    char* ws = (char*)d_ws;
    u16* qb    = (u16*)(ws);
    u16* kb    = (u16*)(ws + MB);
    u16* vTb   = (u16*)(ws + 2 * MB);
    u16* gateb = (u16*)(ws + 3 * MB);
    u16* wavg  = (u16*)(ws + 4 * MB);
    u16* wt    = (u16*)(ws + 5 * MB);             // 5 x 128KB
    float* nb2 = (float*)(ws + 5 * MB + 655360);  // 4.7MB
    u16* Wtq = wt, *Wtk = wt + 65536, *Wtv = wt + 2 * 65536,
       *Wtg = wt + 3 * 65536, *Wto = wt + 4 * 65536;

    prep_w<<<dim3(4, 4, 5), 256, 0, stream>>>(q_w, k_w, v_w, g_w, o_w, wt);
    prep_nb<<<1152, 256, 0, stream>>>(nbias, nb2);
    proj_kernel<0><<<768, 256, 0, stream>>>(q_data, nullptr, Wtq, Wtg, g_b, nullptr,
                                            qb, gateb, nullptr, nullptr);
    proj_kernel<1><<<768, 256, 0, stream>>>(m_data, nullptr, Wtk, Wtv, nullptr, nullptr,
                                            kb, nullptr, vTb, nullptr);

    const int ATTN_SMEM = 2 * 40960;  // 80 KB
    hipFuncSetAttribute((const void*)attn_kernel,
                        hipFuncAttributeMaxDynamicSharedMemorySize, ATTN_SMEM);
    attn_kernel<<<768, 512, ATTN_SMEM, stream>>>(qb, kb, vTb, gateb, bias, nb2, wavg);

    proj_kernel<2><<<768, 256, 0, stream>>>(nullptr, wavg, Wto, nullptr, nullptr, o_b,
                                            nullptr, nullptr, nullptr, out);
}